// Round 1
// baseline (144.128 us; speedup 1.0000x reference)
//
#include <hip/hip_runtime.h>
#include <math.h>

// KTVLoss: inputs out_l, out_r, input_i : (8,3,512,512) fp32. Output: 1 fp32 scalar.
//
// norm part: Sx = 10x10 box sum of |dI/dh| (shape 502x503), Sy = box sum of |dI/dw|
// (shape 503x502). Reference adds them by FLAT index: Sx(i,j) pairs with
// Sy(i, i+j) if i+j<502 else Sy(i+1, i+j-502).
// ratio = (Sx_l+Sy_l+Sx_r+Sy_r) / (Sx_i+Sy_i + 100*EPS), mean over 24*502*503.
// grad part: mean|Gx_l+Gx_r-Gx_i| over 24*511*512 + mean|Gy_l+Gy_r-Gy_i| over same count.
//
// One block per (image, band of RB Sx-rows); 512 threads = 1 per column.
// Streaming box filter: horizontal 10-tap via LDS row, vertical 10-row via
// register ring buffers (loop unrolled by 10 => static ring indices).

namespace {

constexpr int H = 512;
constexpr int W = 512;
constexpr int KW = 10;
constexpr int CX = W - KW + 1;      // 503 Sx columns
constexpr int CY = W - KW;          // 502 Sy columns (and Sy rows-1)
constexpr int RB = 24;              // Sx rows per band
constexpr int NBANDS = (CY + RB - 1) / RB;   // 21 (bands over 502 Sx rows)
constexpr int NSTEPS = RB + KW;     // 34
constexpr int NIMG = 24;            // 8*3
constexpr int NBLOCKS = NIMG * NBANDS;       // 504

// One streaming step. S, UX, UY must be compile-time-foldable after unroll.
#define STEP(S, UX, UY)                                                          \
  {                                                                              \
    const int r = i0 + (S);                                                      \
    const bool rv = (r < H);                                                     \
    float xl = 0.f, xr = 0.f, xi = 0.f;                                          \
    if (rv) {                                                                    \
      const size_t o = (size_t)r * W + j;                                        \
      xl = pL[o]; xr = pR[o]; xi = pI[o];                                        \
    }                                                                            \
    const float gxl = xl - prevL, gxr = xr - prevR, gxi = xi - prevI;            \
    prevL = xl; prevR = xr; prevI = xi;                                          \
    __syncthreads();                                                             \
    xs0[j] = xl; xs1[j] = xr; xs2[j] = xi;                                       \
    if (rv) {                                                                    \
      xgrow[j] = make_float2(fabsf(gxl) + fabsf(gxr), fabsf(gxi));               \
      if (r - 1 < gxEnd) accGX += fabsf(gxl + gxr - gxi);                        \
    }                                                                            \
    __syncthreads();                                                             \
    if (rv && j < W - 1) {                                                       \
      const float gyl = xs0[j + 1] - xl;                                         \
      const float gyr = xs1[j + 1] - xr;                                         \
      const float gyi = xs2[j + 1] - xi;                                         \
      yrow[j] = make_float2(fabsf(gyl) + fabsf(gyr), fabsf(gyi));                \
      if (r < gyEnd) accGY += fabsf(gyl + gyr - gyi);                            \
    }                                                                            \
    __syncthreads();                                                             \
    if (rv && j < CY) {                                                          \
      float hn = 0.f, hd = 0.f;                                                  \
      _Pragma("unroll")                                                          \
      for (int tt = 0; tt < KW; ++tt) {                                          \
        const float2 v = yrow[j + tt];                                           \
        hn += v.x; hd += v.y;                                                    \
      }                                                                          \
      runYN += hn - histYN[UY]; histYN[UY] = hn;                                 \
      runYD += hd - histYD[UY]; histYD[UY] = hd;                                 \
      const int iY = r - (KW - 1);                                               \
      if (iY >= i0) syring[(iY & 1) * CY + j] = make_float2(runYN, runYD);       \
    }                                                                            \
    if (rv && j < CX) {                                                          \
      float gn = 0.f, gd = 0.f;                                                  \
      _Pragma("unroll")                                                          \
      for (int tt = 0; tt < KW; ++tt) {                                          \
        const float2 v = xgrow[j + tt];                                          \
        gn += v.x; gd += v.y;                                                    \
      }                                                                          \
      runXN += gn - histXN[UX]; histXN[UX] = gn;                                 \
      runXD += gd - histXD[UX]; histXD[UX] = gd;                                 \
    }                                                                            \
    __syncthreads();                                                             \
    const int iX = r - KW;                                                       \
    if (rv && j < CX && iX >= i0 && iX < sxEnd) {                                \
      int jy = iX + j;                                                           \
      int rw = iX;                                                               \
      if (jy >= CY) { jy -= CY; ++rw; }                                          \
      const float2 sy = syring[(rw & 1) * CY + jy];                              \
      accN += (runXN + sy.x) / (runXD + sy.y + 1e-4f);                           \
    }                                                                            \
  }

} // namespace

__global__ __launch_bounds__(512) void ktv_main(const float* __restrict__ L,
                                                const float* __restrict__ R,
                                                const float* __restrict__ I,
                                                double* __restrict__ partial) {
  const int blk = blockIdx.x;
  const int img = blk / NBANDS;
  const int band = blk % NBANDS;
  const int i0 = band * RB;
  const int j = threadIdx.x;  // column, 0..511

  // ownership ranges (each global row counted by exactly one band)
  const bool last = (band == NBANDS - 1);
  const int gyEnd = last ? H : (i0 + RB);        // Gy rows [i0, gyEnd)
  const int gxEnd = last ? (H - 1) : (i0 + RB);  // Gx rows [i0, gxEnd)
  const int sxEnd = last ? CY : (i0 + RB);       // Sx rows [i0, sxEnd)  (CY==502)

  const size_t base = (size_t)img * H * W;
  const float* pL = L + base;
  const float* pR = R + base;
  const float* pI = I + base;

  __shared__ float xs0[W], xs1[W], xs2[W];  // current input row, 3 inputs
  __shared__ float2 yrow[W];                // (|gy_l|+|gy_r|, |gy_i|) for row r
  __shared__ float2 xgrow[W];               // (|gx_l|+|gx_r|, |gx_i|) for row r-1
  __shared__ float2 syring[2 * CY];         // last two completed Sy rows (n,d)
  __shared__ float redN[8], redGX[8], redGY[8];

  float histYN[KW], histYD[KW], histXN[KW], histXD[KW];
#pragma unroll
  for (int tt = 0; tt < KW; ++tt) {
    histYN[tt] = 0.f; histYD[tt] = 0.f; histXN[tt] = 0.f; histXD[tt] = 0.f;
  }
  float runYN = 0.f, runYD = 0.f, runXN = 0.f, runXD = 0.f;
  float accN = 0.f, accGX = 0.f, accGY = 0.f;
  float prevL, prevR, prevI;

  // ---- prologue: s = 0 (row i0): Gy only ----
  {
    const size_t o = (size_t)i0 * W + j;
    const float xl = pL[o], xr = pR[o], xi = pI[o];
    prevL = xl; prevR = xr; prevI = xi;
    xs0[j] = xl; xs1[j] = xr; xs2[j] = xi;
    __syncthreads();
    if (j < W - 1) {
      const float gyl = xs0[j + 1] - xl;
      const float gyr = xs1[j + 1] - xr;
      const float gyi = xs2[j + 1] - xi;
      yrow[j] = make_float2(fabsf(gyl) + fabsf(gyr), fabsf(gyi));
      accGY += fabsf(gyl + gyr - gyi);  // row i0 is owned
    }
    __syncthreads();
    if (j < CY) {
      float hn = 0.f, hd = 0.f;
#pragma unroll
      for (int tt = 0; tt < KW; ++tt) {
        const float2 v = yrow[j + tt];
        hn += v.x; hd += v.y;
      }
      runYN = hn; histYN[0] = hn;
      runYD = hd; histYD[0] = hd;
    }
  }

  // ---- main loop: s = 1 .. NSTEPS-1, unrolled by 10 for static ring slots ----
#pragma unroll 1
  for (int t = 0; t < (NSTEPS + 8) / 10; ++t) {
    const int sbase = 1 + t * 10;
#pragma unroll
    for (int u0 = 0; u0 < 10; ++u0) {
      const int s = sbase + u0;
      if (s < NSTEPS) {
        STEP(s, (u0), ((u0 + 1) % 10));
      }
    }
  }

  // ---- block reduction ----
#pragma unroll
  for (int off = 32; off > 0; off >>= 1) {
    accN  += __shfl_down(accN, off);
    accGX += __shfl_down(accGX, off);
    accGY += __shfl_down(accGY, off);
  }
  const int wv = j >> 6;
  if ((j & 63) == 0) { redN[wv] = accN; redGX[wv] = accGX; redGY[wv] = accGY; }
  __syncthreads();
  if (j == 0) {
    float n = 0.f, gx = 0.f, gy = 0.f;
#pragma unroll
    for (int w2 = 0; w2 < 8; ++w2) { n += redN[w2]; gx += redGX[w2]; gy += redGY[w2]; }
    double* p = partial + (size_t)blk * 3;
    p[0] = (double)n; p[1] = (double)gx; p[2] = (double)gy;
  }
}

__global__ __launch_bounds__(64) void ktv_reduce(const double* __restrict__ partial,
                                                 float* __restrict__ out) {
  double n = 0.0, gx = 0.0, gy = 0.0;
  for (int i = threadIdx.x; i < NBLOCKS; i += 64) {
    const double* p = partial + (size_t)i * 3;
    n += p[0]; gx += p[1]; gy += p[2];
  }
#pragma unroll
  for (int off = 32; off > 0; off >>= 1) {
    n  += __shfl_down(n, off);
    gx += __shfl_down(gx, off);
    gy += __shfl_down(gy, off);
  }
  if (threadIdx.x == 0) {
    const double norm_loss = n / 6060144.0;          // 24*502*503
    const double grad_loss = (gx + gy) / 6279168.0;  // 24*511*512
    out[0] = (float)(1e-4 * norm_loss + grad_loss);
  }
}

extern "C" void kernel_launch(void* const* d_in, const int* in_sizes, int n_in,
                              void* d_out, int out_size, void* d_ws, size_t ws_size,
                              hipStream_t stream) {
  (void)in_sizes; (void)n_in; (void)out_size; (void)ws_size;
  const float* L = (const float*)d_in[0];
  const float* R = (const float*)d_in[1];
  const float* I = (const float*)d_in[2];
  double* partial = (double*)d_ws;   // NBLOCKS*3 doubles = 12096 B
  float* out = (float*)d_out;

  hipLaunchKernelGGL(ktv_main, dim3(NBLOCKS), dim3(512), 0, stream, L, R, I, partial);
  hipLaunchKernelGGL(ktv_reduce, dim3(1), dim3(64), 0, stream, partial, out);
}

// Round 2
// 142.449 us; speedup vs baseline: 1.0118x; 1.0118x over previous
//
#include <hip/hip_runtime.h>
#include <math.h>

// KTVLoss: inputs out_l, out_r, input_i : (8,3,512,512) fp32. Output: 1 fp32 scalar.
//
// Sx = 10x10 box sum of |dI/dh| (502x503), Sy = box sum of |dI/dw| (503x502).
// Reference pairs them by FLAT index: Sx(i,j) with Sy(i,i+j) if i+j<502 else
// Sy(i+1,i+j-502). ratio = (SxL+SyL+SxR+SyR)/(SxI+SyI+1e-4), mean over 24*502*503.
// grad part: mean|GxL+GxR-GxI| + mean|GyL+GyR-GyI|, each over 24*511*512.
//
// One block per (image, band of RB Sx rows); 512 threads = 1 per column.
// Per streamed row: horizontal 10-window via DPP row-prefix scan (VALU) +
// 2 ds_bpermute per component; cross-wave boundary (9 lanes/wave) patched via
// small LDS array. Vertical 10-window via register ring buffers (unroll-by-10
// => static ring indices). Sy rows kept in a depth-4 LDS ring; the Sx<->Sy
// flat pairing is read one step delayed so each step has a SINGLE barrier.

namespace {

constexpr int H = 512, W = 512, KW = 10;
constexpr int CX = W - KW + 1;   // 503 Sx cols (and Sy rows)
constexpr int CY = W - KW;       // 502 Sy cols
constexpr int RB = 24;           // Sx rows per band
constexpr int NBANDS = (CY + RB - 1) / RB;   // 21
constexpr int NIMG = 24;                     // 8*3
constexpr int NBLOCKS = NIMG * NBANDS;       // 504

template <int CTRL>
__device__ __forceinline__ float dpp_add_shr(float v) {
  int s = __builtin_amdgcn_update_dpp(0, __float_as_int(v), CTRL, 0xf, 0xf, true);
  return v + __int_as_float(s);
}
__device__ __forceinline__ float dpp_shr1(float v) {
  int s = __builtin_amdgcn_update_dpp(0, __float_as_int(v), 0x111, 0xf, 0xf, true);
  return __int_as_float(s);
}
// inclusive prefix within each 16-lane row (row_shr:1,2,4,8)
__device__ __forceinline__ float row_prefix(float v) {
  v = dpp_add_shr<0x111>(v);
  v = dpp_add_shr<0x112>(v);
  v = dpp_add_shr<0x114>(v);
  v = dpp_add_shr<0x118>(v);
  return v;
}

}  // namespace

// One streaming step. S: step index expr; U: ring slot (S % 10, static).
#define STEP(S, U)                                                               \
  {                                                                              \
    const int s_ = (S);                                                          \
    const int r = i0 + s_;                                                       \
    const bool rv = (r < H);                                                     \
    const int o = off;                                                           \
    off += W;                                                                    \
    float xl = prevL, xr = prevR, xi = prevI;                                    \
    if (rv) { xl = pL[o]; xr = pR[o]; xi = pI[o]; }                              \
    float nxl = __shfl_down(xl, 1);                                              \
    float nxr = __shfl_down(xr, 1);                                              \
    float nxi = __shfl_down(xi, 1);                                              \
    if (rv && lane == 63 && j < W - 1) {                                         \
      nxl = pL[o + 1]; nxr = pR[o + 1]; nxi = pI[o + 1];                         \
    }                                                                            \
    const float gyl = nxl - xl, gyr = nxr - xr, gyi = nxi - xi;                  \
    const float gxl = xl - prevL, gxr = xr - prevR, gxi = xi - prevI;            \
    prevL = xl; prevR = xr; prevI = xi;                                          \
    float yn = fabsf(gyl) + fabsf(gyr), yd = fabsf(gyi);                         \
    float xn = fabsf(gxl) + fabsf(gxr), xd = fabsf(gxi);                         \
    if (s_ == 0) { xn = 0.f; xd = 0.f; }                                         \
    if (!rv) { yn = 0.f; yd = 0.f; xn = 0.f; xd = 0.f; }                         \
    if (j == W - 1) { yn = 0.f; yd = 0.f; }                                      \
    if (rv && r < gyEnd && j < W - 1) accGY += fabsf(gyl + gyr - gyi);           \
    if (s_ > 0 && rv && (r - 1) < gxEnd) accGX += fabsf(gxl + gxr - gxi);        \
    /* horizontal 10-window via per-16-row prefix scan */                        \
    const float Ayn = row_prefix(yn), Ayd = row_prefix(yd);                      \
    const float Axn = row_prefix(xn), Axd = row_prefix(xd);                      \
    const int i9 = lane + 9, i15 = lane | 15;                                    \
    const float t9yn = __shfl(Ayn, i9), t9yd = __shfl(Ayd, i9);                  \
    const float t9xn = __shfl(Axn, i9), t9xd = __shfl(Axd, i9);                  \
    const float Tyn = __shfl(Ayn, i15), Tyd = __shfl(Ayd, i15);                  \
    const float Txn = __shfl(Axn, i15), Txd = __shfl(Axd, i15);                  \
    const float eyn = dpp_shr1(Ayn), eyd = dpp_shr1(Ayd);                        \
    const float exn = dpp_shr1(Axn), exd = dpp_shr1(Axd);                        \
    const bool cross = ((lane & 15) >= 7);                                       \
    float hyn = t9yn - eyn + (cross ? Tyn : 0.f);                                \
    float hyd = t9yd - eyd + (cross ? Tyd : 0.f);                                \
    float hxn = t9xn - exn + (cross ? Txn : 0.f);                                \
    float hxd = t9xd - exd + (cross ? Txd : 0.f);                                \
    if (lane <= 8) bnd[s_ & 1][wv][lane] = make_float4(Ayn, Ayd, Axn, Axd);      \
    /* delayed accN: pre-update runX == Sx row r-11; Sy rows r-11,r-10 ready */  \
    if (s_ >= 11) {                                                              \
      const int iX = r - 11;                                                     \
      if (iX < sxEnd && j < CX) {                                                \
        int jy = iX + j, rw = iX;                                                \
        if (jy >= CY) { jy -= CY; ++rw; }                                        \
        const float2 sy = syring[rw & 3][jy];                                    \
        const float num = runXN + sy.x;                                          \
        const float den = runXD + sy.y + 1e-4f;                                  \
        accN += num * __builtin_amdgcn_rcpf(den);                                \
      }                                                                          \
    }                                                                            \
    __syncthreads();                                                             \
    /* cross-wave boundary patch: lanes 55..63 window spills into next wave */   \
    if (lane >= 55 && wv < 7) {                                                  \
      const float4 Ap = bnd[s_ & 1][wv + 1][lane - 55];                          \
      hyn = Ap.x - eyn + Tyn;                                                    \
      hyd = Ap.y - eyd + Tyd;                                                    \
      hxn = Ap.z - exn + Txn;                                                    \
      hxd = Ap.w - exd + Txd;                                                    \
    }                                                                            \
    runYN += hyn - histYN[U]; histYN[U] = hyn;                                   \
    runYD += hyd - histYD[U]; histYD[U] = hyd;                                   \
    runXN += hxn - histXN[U]; histXN[U] = hxn;                                   \
    runXD += hxd - histXD[U]; histXD[U] = hxd;                                   \
    if (s_ >= 9) {                                                               \
      const int iY = r - 9;                                                      \
      if (iY <= sxEnd && j < CY) syring[iY & 3][j] = make_float2(runYN, runYD);  \
    }                                                                            \
  }

__global__ __launch_bounds__(512, 4) void ktv_main(const float* __restrict__ L,
                                                   const float* __restrict__ R,
                                                   const float* __restrict__ I,
                                                   double* __restrict__ partial) {
  const int blk = blockIdx.x;
  const int img = blk / NBANDS;
  const int band = blk % NBANDS;
  const int i0 = band * RB;
  const int j = threadIdx.x;  // column
  const int lane = j & 63;
  const int wv = j >> 6;

  const bool lastb = (band == NBANDS - 1);
  const int gyEnd = lastb ? H : (i0 + RB);        // Gy rows owned: [i0, gyEnd)
  const int gxEnd = lastb ? (H - 1) : (i0 + RB);  // Gx rows owned: [i0, gxEnd)
  const int sxEnd = lastb ? CY : (i0 + RB);       // Sx rows owned: [i0, sxEnd)
  const int smax = sxEnd - i0 + 11;               // last output at s = smax-1

  const size_t base = (size_t)img * (H * W);
  const float* pL = L + base;
  const float* pR = R + base;
  const float* pI = I + base;

  __shared__ float2 syring[4][CY];   // completed Sy rows (n,d), depth-4 ring
  __shared__ float4 bnd[2][8][9];    // per-wave lanes 0..8 prefix, dbuffered
  __shared__ float redN[8], redGX[8], redGY[8];

  float histYN[KW], histYD[KW], histXN[KW], histXD[KW];
#pragma unroll
  for (int tt = 0; tt < KW; ++tt) {
    histYN[tt] = 0.f; histYD[tt] = 0.f; histXN[tt] = 0.f; histXD[tt] = 0.f;
  }
  float runYN = 0.f, runYD = 0.f, runXN = 0.f, runXD = 0.f;
  float accN = 0.f, accGX = 0.f, accGY = 0.f;
  float prevL = 0.f, prevR = 0.f, prevI = 0.f;
  int off = i0 * W + j;

  const int tmax = (smax + 9) / 10;
#pragma unroll 1
  for (int t = 0; t < tmax; ++t) {
    const int sb = t * 10;
    if (sb + 0 < smax) STEP(sb + 0, 0)
    if (sb + 1 < smax) STEP(sb + 1, 1)
    if (sb + 2 < smax) STEP(sb + 2, 2)
    if (sb + 3 < smax) STEP(sb + 3, 3)
    if (sb + 4 < smax) STEP(sb + 4, 4)
    if (sb + 5 < smax) STEP(sb + 5, 5)
    if (sb + 6 < smax) STEP(sb + 6, 6)
    if (sb + 7 < smax) STEP(sb + 7, 7)
    if (sb + 8 < smax) STEP(sb + 8, 8)
    if (sb + 9 < smax) STEP(sb + 9, 9)
  }

  // ---- block reduction ----
#pragma unroll
  for (int o2 = 32; o2 > 0; o2 >>= 1) {
    accN  += __shfl_down(accN, o2);
    accGX += __shfl_down(accGX, o2);
    accGY += __shfl_down(accGY, o2);
  }
  if (lane == 0) { redN[wv] = accN; redGX[wv] = accGX; redGY[wv] = accGY; }
  __syncthreads();
  if (j == 0) {
    float n = 0.f, gx = 0.f, gy = 0.f;
#pragma unroll
    for (int w2 = 0; w2 < 8; ++w2) { n += redN[w2]; gx += redGX[w2]; gy += redGY[w2]; }
    double* p = partial + (size_t)blk * 3;
    p[0] = (double)n; p[1] = (double)gx; p[2] = (double)gy;
  }
}

__global__ __launch_bounds__(64) void ktv_reduce(const double* __restrict__ partial,
                                                 float* __restrict__ out) {
  double n = 0.0, gx = 0.0, gy = 0.0;
  for (int i = threadIdx.x; i < NBLOCKS; i += 64) {
    const double* p = partial + (size_t)i * 3;
    n += p[0]; gx += p[1]; gy += p[2];
  }
#pragma unroll
  for (int o2 = 32; o2 > 0; o2 >>= 1) {
    n  += __shfl_down(n, o2);
    gx += __shfl_down(gx, o2);
    gy += __shfl_down(gy, o2);
  }
  if (threadIdx.x == 0) {
    const double norm_loss = n / 6060144.0;          // 24*502*503
    const double grad_loss = (gx + gy) / 6279168.0;  // 24*511*512
    out[0] = (float)(1e-4 * norm_loss + grad_loss);
  }
}

extern "C" void kernel_launch(void* const* d_in, const int* in_sizes, int n_in,
                              void* d_out, int out_size, void* d_ws, size_t ws_size,
                              hipStream_t stream) {
  (void)in_sizes; (void)n_in; (void)out_size; (void)ws_size;
  const float* L = (const float*)d_in[0];
  const float* R = (const float*)d_in[1];
  const float* I = (const float*)d_in[2];
  double* partial = (double*)d_ws;   // NBLOCKS*3 doubles = 12096 B
  float* out = (float*)d_out;

  hipLaunchKernelGGL(ktv_main, dim3(NBLOCKS), dim3(512), 0, stream, L, R, I, partial);
  hipLaunchKernelGGL(ktv_reduce, dim3(1), dim3(64), 0, stream, partial, out);
}